// Round 4
// baseline (213.478 us; speedup 1.0000x reference)
//
#include <hip/hip_runtime.h>
#include <math.h>

#define HH 512
#define WW 512
#define NPIX (16*HH*WW)
#define RAD 10
#define KS 21
#define TX 64
#define TY 32

typedef unsigned short ushort_t;
typedef unsigned int uint_t;

__device__ __forceinline__ int refl(int v, int n){ v = v < 0 ? -v : v; return v >= n ? 2*n - 2 - v : v; }
__device__ __forceinline__ float sigm(float x){ return 1.f/(1.f+expf(-x)); }
__device__ __forceinline__ ushort_t f2bf(float f){
    uint_t x = __float_as_uint(f);
    return (ushort_t)((x + 0x7fffu + ((x >> 16) & 1u)) >> 16);
}
__device__ __forceinline__ float bf2f(ushort_t h){ return __uint_as_float(((uint_t)h) << 16); }

// P layout: [0]=alpha [1]=lam [2]=beta*sqrt(xi) [3]=eta [4]=nu [5]=gamma [6]=omega
// [8..28]=gauss weights, [64+32*i]=per-image max slots (zeroed every launch)
__global__ void k_params(const float* a_raw, const float* l_raw, const float* lsig,
                         const float* lbeta, const float* lxi, const float* e_raw,
                         const float* n_raw, const float* lgam, const float* o_raw,
                         float* P)
{
    if (threadIdx.x || blockIdx.x) return;
    float sigma = 0.5f + 4.5f*sigm(lsig[0]);
    float beta  = 1.f + 4.f*sigm(lbeta[0]);
    float xi    = 1.f + 4.f*sigm(lxi[0]);
    P[0] = 0.6f + 1.4f*sigm(a_raw[0]);
    P[1] = 0.01f + 0.19f*sigm(l_raw[0]);
    P[2] = beta*sqrtf(xi);
    P[3] = sigm(e_raw[0]);
    P[4] = sigm(n_raw[0]);
    P[5] = 1.f + 3.f*sigm(lgam[0]);
    P[6] = sigm(o_raw[0]);
    float kk[KS], s = 0.f;
    for (int i = 0; i < KS; ++i){ float c = (float)(i-RAD); kk[i] = expf(-c*c/(2.f*sigma*sigma+1e-8f)); s += kk[i]; }
    float inv = 1.f/(s+1e-8f);
    for (int i = 0; i < KS; ++i) P[8+i] = kk[i]*inv;
    for (int i = 0; i < 16; ++i) P[64+32*i] = 0.f;
}

// fractal_weight = clip(1 - omega*lfd, 0, 1), iteration-invariant -> bf16 once
__global__ __launch_bounds__(256)
void k_fw(const float* __restrict__ lfd, ushort_t* __restrict__ fw,
          const float* __restrict__ P)
{
    float omg = P[6];
    int i = blockIdx.x*256 + threadIdx.x;     // float4 index
    float4 v = ((const float4*)lfd)[i];
    ushort4 o;
    o.x = f2bf(fminf(fmaxf(1.f - omg*v.x, 0.f), 1.f));
    o.y = f2bf(fminf(fmaxf(1.f - omg*v.y, 0.f), 1.f));
    o.z = f2bf(fminf(fmaxf(1.f - omg*v.z, 0.f), 1.f));
    o.w = f2bf(fminf(fmaxf(1.f - omg*v.w, 0.f), 1.f));
    ((ushort4*)fw)[i] = o;
}

// Horizontal blur, once per pixel, bf16 output. 4 px/thread.
__global__ __launch_bounds__(256)
void k_hblur(const float* __restrict__ src, ushort_t* __restrict__ dst,
             const float* __restrict__ P)
{
    float kw[KS];
#pragma unroll
    for (int j = 0; j < KS; ++j) kw[j] = P[8+j];
    int i = blockIdx.x*256 + threadIdx.x;   // float4-group index
    int m = i & 127;
    int row = i >> 7;
    const float* rp = src + row*WW;
    float l[32];
    if (m >= 3 && m <= 123){
        const float4* p4 = (const float4*)(rp + 4*m - 12);
#pragma unroll
        for (int q = 0; q < 8; ++q){ float4 v = p4[q]; l[4*q]=v.x; l[4*q+1]=v.y; l[4*q+2]=v.z; l[4*q+3]=v.w; }
    } else {
#pragma unroll
        for (int q = 0; q < 32; ++q) l[q] = rp[refl(4*m-12+q, WW)];
    }
    float a0=0.f, a1=0.f, a2=0.f, a3=0.f;
#pragma unroll
    for (int j = 0; j < KS; ++j){
        float k = kw[j];
        a0 = fmaf(k, l[j+2], a0);
        a1 = fmaf(k, l[j+3], a1);
        a2 = fmaf(k, l[j+4], a2);
        a3 = fmaf(k, l[j+5], a3);
    }
    ushort4 o; o.x=f2bf(a0); o.y=f2bf(a1); o.z=f2bf(a2); o.w=f2bf(a3);
    *(ushort4*)(dst + row*WW + 4*m) = o;
}

// Fused v-blur + phi + update (+ final-iter residual & max).
__global__ __launch_bounds__(256, 6)
void k_fused(const float* __restrict__ u, const ushort_t* __restrict__ tmp,
             const float* __restrict__ img, const ushort_t* __restrict__ fw,
             float* __restrict__ dst, float* __restrict__ resid,
             const float* __restrict__ P, float* Pmax, int do_max)
{
    __shared__ float su[36][68];
    __shared__ float pt[34][68];
    __shared__ float red[4];
    const int tid = threadIdx.x;
    const int x0 = blockIdx.x*TX, y0 = blockIdx.y*TY, b = blockIdx.z;
    const ushort_t* tb = tmp + (b<<18);
    const float*    ub = u   + (b<<18);
    const float*    ib = img + (b<<18);
    const ushort_t* fb = fw  + (b<<18);
    float* db = dst + (b<<18);

    float kw[KS];
#pragma unroll
    for (int j = 0; j < KS; ++j) kw[j] = P[8+j];
    const float alpha=P[0], lam=P[1], bsx=P[2], eta=P[3], nu=P[4], gam=P[5];
    const bool yint = (y0 >= 32) && (y0 <= 448);
    const bool xint = (x0 >= 64) && (x0 <= 384);

    // --- vertical blur from global bf16 tmp: 9 row-groups x 68 cols ---
#pragma unroll
    for (int p = 0; p < 3; ++p){
        int i = tid + p*256;
        if (i < 612){
            int rg = i/68, c = i - rg*68;
            int xc = x0 - 2 + c;
            if (!xint) xc = refl(xc, WW);
            int yb = y0 - 12 + rg*4;
            float w[24];
            if (yint){
                const ushort_t* cp = tb + yb*WW + xc;
#pragma unroll
                for (int q = 0; q < 24; ++q) w[q] = bf2f(cp[q*WW]);
            } else {
#pragma unroll
                for (int q = 0; q < 24; ++q) w[q] = bf2f(tb[refl(yb+q, HH)*WW + xc]);
            }
            float a0=0.f, a1=0.f, a2=0.f, a3=0.f;
#pragma unroll
            for (int j = 0; j < KS; ++j){
                float k = kw[j];
                a0 = fmaf(k, w[j],   a0);
                a1 = fmaf(k, w[j+1], a1);
                a2 = fmaf(k, w[j+2], a2);
                a3 = fmaf(k, w[j+3], a3);
            }
            int r0 = rg*4;
            su[r0][c]=a0; su[r0+1][c]=a1; su[r0+2][c]=a2; su[r0+3][c]=a3;
        }
    }
    __syncthreads();

    // --- phi: 34 x 66 ---
#pragma unroll
    for (int p = 0; p < 9; ++p){
        int i = tid + p*256;
        if (i < 2244){
            int r = i/66, c = i - r*66;
            float gys = (su[r+2][c+1] - su[r][c+1])*0.5f;
            float gxs = (su[r+1][c+2] - su[r+1][c])*0.5f;
            float d = fmaf(eta, fmaf(gxs,gxs, fmaf(gys,gys, 1e-8f)), 1e-6f);
            float ph = fminf(bsx*rsqrtf(d), 10.f);
            int py = y0-1+r, px = x0-1+c;
            if (!yint) py = refl(py, HH);
            if (!xint) px = refl(px, WW);
            pt[r][c] = ph*bf2f(fb[py*WW+px]);
        }
    }
    __syncthreads();

    // --- update: each wave owns 8 consecutive rows; u rolls through registers ---
    const int c = tid & 63, r00 = tid >> 6;
    const int gx = x0 + c;
    const int gy0 = y0 + r00*8;
    const int xm0 = (x0 > 0) ? x0 - 1 : 1;
    const int xp0 = (x0 + TX < WW) ? x0 + TX : WW - 2;
    float mymax = 0.f;

    int ym = yint ? gy0-1 : refl(gy0-1, HH);
    float um  = ub[ym*WW + gx];
    float uc0 = ub[gy0*WW + gx];
#pragma unroll
    for (int p = 0; p < 8; ++p){
        int gy = gy0 + p;
        int yp = yint ? gy+1 : refl(gy+1, HH);
        float us0 = ub[yp*WW + gx];
        float uw = __shfl_up(uc0, 1);
        float ue = __shfl_down(uc0, 1);
        if (c == 0)  uw = ub[gy*WW + xm0];
        if (c == 63) ue = ub[gy*WW + xp0];

        float gyv = (us0-um)*0.5f, gxv = (ue-uw)*0.5f;
        float lap = um+us0+ue+uw - 4.f*uc0;
        float gm = sqrtf(fmaf(gxv,gxv, fmaf(gyv,gyv, 1e-8f)));
        float s = gm*fabsf(lap);
        float psi = 1e-4f*sqrtf(fmaf(nu, s*s*s, gam));
        int rr = r00*8 + p;
        float pN = pt[rr][c+1], pS = pt[rr+2][c+1], pE = pt[rr+1][c+2], pW = pt[rr+1][c];
        float dv = pN*(um-uc0) + pS*(us0-uc0) + pE*(ue-uc0) + pW*(uw-uc0);
        int idx = gy*WW + gx;
        float u0v = ib[idx];
        float du = alpha*psi*dv - lam*(uc0-u0v);
        float un = fminf(fmaxf(fmaf(0.1f, du, uc0), 0.f), 1.f);
        db[idx] = un;
        if (do_max){
            float v = fabsf(u0v - un);
            resid[(b<<18)+idx] = v;
            mymax = fmaxf(mymax, v);
        }
        um = uc0; uc0 = us0;
    }
    if (do_max){
#pragma unroll
        for (int off = 32; off; off >>= 1) mymax = fmaxf(mymax, __shfl_down(mymax, off));
        if ((tid & 63) == 0) red[tid>>6] = mymax;
        __syncthreads();
        if (tid == 0){
            float m = fmaxf(fmaxf(red[0],red[1]), fmaxf(red[2],red[3]));
            atomicMax((unsigned int*)(Pmax + 32*b), __float_as_uint(m));
        }
    }
}

// in-place normalize of residual
__global__ void k_res2(float* __restrict__ r, const float* __restrict__ Pmax)
{
    int i = blockIdx.x*256 + threadIdx.x;   // float4 index
    int b = i >> 16;
    float inv = 1.f/(Pmax[32*b] + 1e-8f);
    float4 v = ((const float4*)r)[i];
    v.x *= inv; v.y *= inv; v.z *= inv; v.w *= inv;
    ((float4*)r)[i] = v;
}

extern "C" void kernel_launch(void* const* d_in, const int* in_sizes, int n_in,
                              void* d_out, int out_size, void* d_ws, size_t ws_size,
                              hipStream_t stream)
{
    const float* image = (const float*)d_in[0];
    const float* lfd   = (const float*)d_in[1];

    float* out_u = (float*)d_out;
    float* out_r = out_u + NPIX;

    ushort_t* tmp = (ushort_t*)d_ws;            // NPIX bf16: h-blur output
    ushort_t* fwb = tmp + NPIX;                 // NPIX bf16: fractal weight
    float*    uB  = (float*)(fwb + NPIX);       // NPIX f32 ping-pong
    float*    P   = uB + NPIX;                  // params + max slots

    k_params<<<1, 64, 0, stream>>>((const float*)d_in[2], (const float*)d_in[3],
                                   (const float*)d_in[4], (const float*)d_in[5],
                                   (const float*)d_in[6], (const float*)d_in[7],
                                   (const float*)d_in[8], (const float*)d_in[9],
                                   (const float*)d_in[10], P);
    k_fw<<<NPIX/1024, 256, 0, stream>>>(lfd, fwb, P);

    dim3 grd(WW/TX, HH/TY, 16), blk(256);
    float* Pmax = P + 64;
    for (int it = 0; it < 5; ++it){
        const float* src = (it == 0) ? image : ((it & 1) ? out_u : uB);
        float* dstp = (it & 1) ? uB : out_u;
        k_hblur<<<4096, 256, 0, stream>>>(src, tmp, P);
        k_fused<<<grd, blk, 0, stream>>>(src, tmp, image, fwb, dstp, out_r, P, Pmax, it == 4 ? 1 : 0);
    }
    k_res2<<<NPIX/1024, 256, 0, stream>>>(out_r, Pmax);
}

// Round 5
// 84.281 us; speedup vs baseline: 2.5329x; 2.5329x over previous
//
#include <hip/hip_runtime.h>
#include <math.h>

#define HH 512
#define WW 512
#define NPIX (16*HH*WW)
#define RAD 10
#define KS 21
#define TX 64
#define TY 32
// mega tile: 64x32 output + radius-5 ghost ring
#define TW 74
#define TH 42
#define TLW 76   // LDS row stride

__device__ __forceinline__ int refl(int v, int n){ v = v < 0 ? -v : v; return v >= n ? 2*n - 2 - v : v; }
__device__ __forceinline__ float sigm(float x){ return 1.f/(1.f+expf(-x)); }

// P layout: [0]=alpha [1]=lam [2]=beta [3]=xi [4]=eta [5]=nu [6]=gamma [7]=omega
// [8..28]=gauss weights  [30]=saturation flag  [64+32*i]=per-image max slots
__global__ void k_params(const float* a_raw, const float* l_raw, const float* lsig,
                         const float* lbeta, const float* lxi, const float* e_raw,
                         const float* n_raw, const float* lgam, const float* o_raw,
                         float* P)
{
    if (threadIdx.x || blockIdx.x) return;
    float sigma = 0.5f + 4.5f*sigm(lsig[0]);
    float beta  = 1.f + 4.f*sigm(lbeta[0]);
    float xi    = 1.f + 4.f*sigm(lxi[0]);
    float eta   = sigm(e_raw[0]);
    P[0] = 0.6f + 1.4f*sigm(a_raw[0]);
    P[1] = 0.01f + 0.19f*sigm(l_raw[0]);
    P[2] = beta;
    P[3] = xi;
    P[4] = eta;
    P[5] = sigm(n_raw[0]);
    P[6] = 1.f + 3.f*sigm(lgam[0]);
    P[7] = sigm(o_raw[0]);
    float kk[KS], s = 0.f;
    for (int i = 0; i < KS; ++i){ float c = (float)(i-RAD); kk[i] = expf(-c*c/(2.f*sigma*sigma+1e-8f)); s += kk[i]; }
    float inv = 1.f/(s+1e-8f);
    for (int i = 0; i < KS; ++i) P[8+i] = kk[i]*inv;
    // phi saturates at 10 for ALL possible u in [0,1] iff beta^2*xi >= 100*(eta*g2max+1e-6),
    // g2max = 0.5 (+fp margin): central diffs of convex-averaged clipped u are in [-0.5,0.5].
    P[30] = (beta*beta*xi >= 100.f*(eta*0.5000002f + 1e-6f)) ? 1.f : 0.f;
    for (int i = 0; i < 16; ++i) P[64+32*i] = 0.f;
}

// Saturated-phi path: all 5 iterations in one kernel, radius-5 ghost-cell tile.
// Exact: phi==10.0 (clamped) so u_sigma never enters; phi_f = 10*fw, iteration-invariant.
// Reflect ghost staging is exact: stencil is mirror-symmetric (gradients appear squared).
__global__ __launch_bounds__(256, 4)
void k_mega(const float* __restrict__ img, const float* __restrict__ lfd,
            float* __restrict__ out_u, const float* __restrict__ P, float* Pmax)
{
    if (P[30] == 0.f) return;
    __shared__ float uA[TH][TLW];
    __shared__ float uB[TH][TLW];
    __shared__ float fwt[TH][TLW];
    __shared__ float red[4];
    const int tid = threadIdx.x;
    const int x0 = blockIdx.x*TX - 5, y0 = blockIdx.y*TY - 5;
    const int b = blockIdx.z;
    const float* ib = img + (b<<18);
    const float* lb = lfd + (b<<18);
    float* ob = out_u + (b<<18);
    const float a10 = 10.f*P[0], lam = P[1], nu = P[5], gam = P[6], omg = P[7];
    const bool bord = (blockIdx.x == 0) | (blockIdx.x == (WW/TX - 1)) |
                      (blockIdx.y == 0) | (blockIdx.y == (HH/TY - 1));

    // stage u0 and fw (74 x 42), reflected at borders
    for (int i = tid; i < TW*TH; i += 256){
        int r = i / TW, c = i - r*TW;
        int gx = x0 + c, gy = y0 + r;
        if (bord){ gx = refl(gx, WW); gy = refl(gy, HH); }
        int gi = gy*WW + gx;
        float u0 = ib[gi];
        uA[r][c] = u0;
        fwt[r][c] = fminf(fmaxf(1.f - omg*lb[gi], 0.f), 1.f);
    }
    __syncthreads();

    float mymax = 0.f;

#define DIFF_ITER(K, S, D, LAST) { \
    constexpr int w_ = TW - 2*(K), h_ = TH - 2*(K); \
    for (int i = tid; i < w_*h_; i += 256){ \
        int r = i / w_, c = i - r*w_; \
        int rr = r + (K), cc = c + (K); \
        float uc = S[rr][cc]; \
        float uN = S[rr-1][cc], uS = S[rr+1][cc]; \
        float uE = S[rr][cc+1], uW = S[rr][cc-1]; \
        float gyv = (uS-uN)*0.5f, gxv = (uE-uW)*0.5f; \
        float lap = uN+uS+uE+uW - 4.f*uc; \
        float gm = sqrtf(fmaf(gxv,gxv, fmaf(gyv,gyv, 1e-8f))); \
        float sv = gm*fabsf(lap); \
        float psi = 1e-4f*sqrtf(fmaf(nu, sv*sv*sv, gam)); \
        float dv = fwt[rr-1][cc]*(uN-uc) + fwt[rr+1][cc]*(uS-uc) \
                 + fwt[rr][cc+1]*(uE-uc) + fwt[rr][cc-1]*(uW-uc); \
        int gx = x0 + cc, gy = y0 + rr; \
        if (bord){ gx = refl(gx, WW); gy = refl(gy, HH); } \
        float u0v = ib[gy*WW + gx]; \
        float du = fmaf(a10*psi, dv, -lam*(uc - u0v)); \
        float un = fminf(fmaxf(fmaf(0.1f, du, uc), 0.f), 1.f); \
        if (LAST){ ob[gy*WW + gx] = un; mymax = fmaxf(mymax, fabsf(u0v - un)); } \
        else D[rr][cc] = un; \
    } \
    __syncthreads(); }

    DIFF_ITER(1, uA, uB, 0)
    DIFF_ITER(2, uB, uA, 0)
    DIFF_ITER(3, uA, uB, 0)
    DIFF_ITER(4, uB, uA, 0)
    DIFF_ITER(5, uA, uB, 1)
#undef DIFF_ITER

#pragma unroll
    for (int off = 32; off; off >>= 1) mymax = fmaxf(mymax, __shfl_down(mymax, off));
    if ((tid & 63) == 0) red[tid >> 6] = mymax;
    __syncthreads();
    if (tid == 0){
        float m = fmaxf(fmaxf(red[0],red[1]), fmaxf(red[2],red[3]));
        atomicMax((unsigned int*)(Pmax + 32*b), __float_as_uint(m));
    }
}

// General-path fallback (round-2 fully-fused iteration). Early-exits when saturated.
__global__ __launch_bounds__(256)
void k_iter(const float* __restrict__ src, const float* __restrict__ img,
            const float* __restrict__ lfd, float* __restrict__ dst,
            const float* __restrict__ P, float* Pmax, int do_max)
{
    if (P[30] != 0.f) return;
    __shared__ __attribute__((aligned(16))) float sh[56][72];
    __shared__ float su[36][72];
    __shared__ float ut[34][72];
    __shared__ float red[4];
    float (*pt)[72] = sh;

    const int tid = threadIdx.x;
    const int x0 = blockIdx.x * TX;
    const int y0 = blockIdx.y * TY;
    const int b  = blockIdx.z;
    const float* sb = src + (b << 18);
    const float* ib = img + (b << 18);
    const float* lb = lfd + (b << 18);
    float* db = dst + (b << 18);

    float kw[KS];
#pragma unroll
    for (int j = 0; j < KS; ++j) kw[j] = P[8 + j];
    const float alpha = P[0], lam = P[1], beta = P[2], xi = P[3];
    const float eta = P[4], nu = P[5], gam = P[6], omg = P[7];

#pragma unroll
    for (int p = 0; p < 9; ++p) {
        int i = tid + p * 256;
        if (i < 34 * 66) {
            int r = i / 66, c = i - r * 66;
            ut[r][c] = sb[refl(y0 - 1 + r, HH) * WW + refl(x0 - 1 + c, WW)];
        }
    }
#pragma unroll
    for (int p = 0; p < 4; ++p) {
        int i = tid + p * 256;
        if (i < 56 * 17) {
            int hr = i / 17, g = i - hr * 17;
            const float* row = sb + refl(y0 - 12 + hr, HH) * WW;
            int gxs = x0 - 12 + 4 * g;
            float w[24];
            if (gxs >= 0 && gxs + 23 < WW) {
                const float4* p4 = (const float4*)(row + gxs);
#pragma unroll
                for (int q = 0; q < 6; ++q) {
                    float4 v = p4[q];
                    w[4*q] = v.x; w[4*q+1] = v.y; w[4*q+2] = v.z; w[4*q+3] = v.w;
                }
            } else {
#pragma unroll
                for (int q = 0; q < 24; ++q) w[q] = row[refl(gxs + q, WW)];
            }
            float a0 = 0.f, a1 = 0.f, a2 = 0.f, a3 = 0.f;
#pragma unroll
            for (int j = 0; j < KS; ++j) {
                a0 = fmaf(kw[j], w[j],     a0);
                a1 = fmaf(kw[j], w[j + 1], a1);
                a2 = fmaf(kw[j], w[j + 2], a2);
                a3 = fmaf(kw[j], w[j + 3], a3);
            }
            float4 o; o.x = a0; o.y = a1; o.z = a2; o.w = a3;
            *(float4*)&sh[hr][4 * g] = o;
        }
    }
    __syncthreads();
#pragma unroll
    for (int p = 0; p < 3; ++p) {
        int i = tid + p * 256;
        if (i < 9 * 68) {
            int rg = i / 68, c = i - rg * 68;
            int r0 = rg * 4;
            float a0 = 0.f, a1 = 0.f, a2 = 0.f, a3 = 0.f;
#pragma unroll
            for (int q = 0; q < 24; ++q) {
                float s = sh[r0 + q][c];
                if (q <= 20)           a0 = fmaf(kw[q],     s, a0);
                if (q >= 1 && q <= 21) a1 = fmaf(kw[q - 1], s, a1);
                if (q >= 2 && q <= 22) a2 = fmaf(kw[q - 2], s, a2);
                if (q >= 3)            a3 = fmaf(kw[q - 3], s, a3);
            }
            su[r0][c] = a0; su[r0+1][c] = a1; su[r0+2][c] = a2; su[r0+3][c] = a3;
        }
    }
    __syncthreads();
#pragma unroll
    for (int p = 0; p < 9; ++p) {
        int i = tid + p * 256;
        if (i < 34 * 66) {
            int r = i / 66, c = i - r * 66;
            float gys = (su[r + 2][c + 1] - su[r][c + 1]) * 0.5f;
            float gxs = (su[r + 1][c + 2] - su[r + 1][c]) * 0.5f;
            float g2 = fmaf(gxs, gxs, fmaf(gys, gys, 1e-8f));
            float ph = fminf(beta * sqrtf(xi / fmaf(eta, g2, 1e-6f)), 10.f);
            float lv = lb[refl(y0 - 1 + r, HH) * WW + refl(x0 - 1 + c, WW)];
            float fw = fminf(fmaxf(1.f - omg * lv, 0.f), 1.f);
            pt[r][c] = ph * fw;
        }
    }
    __syncthreads();
    const int c = tid & 63, r0 = tid >> 6;
    float mymax = 0.f;
#pragma unroll
    for (int p = 0; p < 8; ++p) {
        int r = r0 + p * 4;
        float uc = ut[r + 1][c + 1];
        float uN = ut[r][c + 1],     uS = ut[r + 2][c + 1];
        float uE = ut[r + 1][c + 2], uW = ut[r + 1][c];
        float gy = (uS - uN) * 0.5f, gx = (uE - uW) * 0.5f;
        float lap = uN + uS + uE + uW - 4.f * uc;
        float gm = sqrtf(fmaf(gx, gx, fmaf(gy, gy, 1e-8f)));
        float s = gm * fabsf(lap);
        float psi = 1e-4f * sqrtf(fmaf(nu, s * s * s, gam));
        float pN = pt[r][c + 1],     pS = pt[r + 2][c + 1];
        float pE = pt[r + 1][c + 2], pW = pt[r + 1][c];
        float dv = pN * (uN - uc) + pS * (uS - uc) + pE * (uE - uc) + pW * (uW - uc);
        int gidx = (y0 + r) * WW + x0 + c;
        float u0v = ib[gidx];
        float du = alpha * psi * dv - lam * (uc - u0v);
        float un = fminf(fmaxf(fmaf(0.1f, du, uc), 0.f), 1.f);
        db[gidx] = un;
        mymax = fmaxf(mymax, fabsf(u0v - un));
    }
    if (do_max) {
#pragma unroll
        for (int off = 32; off; off >>= 1) mymax = fmaxf(mymax, __shfl_down(mymax, off));
        if ((tid & 63) == 0) red[tid >> 6] = mymax;
        __syncthreads();
        if (tid == 0) {
            float m = fmaxf(fmaxf(red[0], red[1]), fmaxf(red[2], red[3]));
            atomicMax((unsigned int*)(Pmax + 32 * b), __float_as_uint(m));
        }
    }
}

// residual: r = |img - u| / (max + 1e-8), float4
__global__ void k_res2(const float* __restrict__ img, const float* __restrict__ u,
                       float* __restrict__ r, const float* __restrict__ Pmax)
{
    int i = blockIdx.x * 256 + threadIdx.x;   // float4 index
    int b = i >> 16;
    float inv = 1.f / (Pmax[32 * b] + 1e-8f);
    float4 a = ((const float4*)img)[i];
    float4 c = ((const float4*)u)[i];
    float4 o;
    o.x = fabsf(a.x - c.x) * inv;
    o.y = fabsf(a.y - c.y) * inv;
    o.z = fabsf(a.z - c.z) * inv;
    o.w = fabsf(a.w - c.w) * inv;
    ((float4*)r)[i] = o;
}

extern "C" void kernel_launch(void* const* d_in, const int* in_sizes, int n_in,
                              void* d_out, int out_size, void* d_ws, size_t ws_size,
                              hipStream_t stream)
{
    const float* image = (const float*)d_in[0];
    const float* lfd   = (const float*)d_in[1];

    float* out_u = (float*)d_out;
    float* out_r = out_u + NPIX;

    float* uB = (float*)d_ws;           // NPIX floats (fallback ping-pong)
    float* P  = uB + NPIX;              // params + max slots

    k_params<<<1, 64, 0, stream>>>((const float*)d_in[2], (const float*)d_in[3],
                                   (const float*)d_in[4], (const float*)d_in[5],
                                   (const float*)d_in[6], (const float*)d_in[7],
                                   (const float*)d_in[8], (const float*)d_in[9],
                                   (const float*)d_in[10], P);

    float* Pmax = P + 64;
    dim3 grd(WW/TX, HH/TY, 16), blk(256);

    // saturated-phi fast path (no-op if not saturated)
    k_mega<<<grd, blk, 0, stream>>>(image, lfd, out_u, P, Pmax);

    // general fallback (no-op if saturated)
    float* bufs[2] = { out_u, uB };
    for (int it = 0; it < 5; ++it) {
        const float* src = (it == 0) ? image : bufs[(it + 1) & 1];
        float* dstp = bufs[it & 1];
        k_iter<<<grd, blk, 0, stream>>>(src, image, lfd, dstp, P, Pmax, it == 4 ? 1 : 0);
    }

    k_res2<<<NPIX/1024, 256, 0, stream>>>(image, out_u, out_r, Pmax);
}